// Round 4
// baseline (329.361 us; speedup 1.0000x reference)
//
#include <hip/hip_runtime.h>

#define NPTS  32768
#define DIM   256
#define KCB   1024
#define BPTS  256      // points per block tile
#define BK    128      // k per kt iteration
#define DT    32
#define NSPLIT 4       // k-range splits (256 k each, kt loop x2)

#define ZQ_OFF   0
#define LOSS_OFF 8388608
#define IDX_OFF  8388609

// z layout [B, D, H, W]: point n = b*1024 + h*32 + w ; element (n, d) at
// b*262144 + d*1024 + hw
__device__ __forceinline__ int z_base(int n) {
    return ((n >> 10) << 18) | (n & 1023);
}

// ---- numpy pairwise sum (AVX512 npyv order) of squares, 128 elems ----
__device__ __forceinline__ float np_half_sq(const float* __restrict__ p, int stride) {
    float S[16];
#pragma unroll
    for (int l = 0; l < 16; ++l) {
        float t[8];
#pragma unroll
        for (int j = 0; j < 8; ++j) {
            float v = p[(j * 16 + l) * stride];
            t[j] = __fmul_rn(v, v);
        }
        S[l] = __fadd_rn(__fadd_rn(__fadd_rn(t[0], t[1]), __fadd_rn(t[2], t[3])),
                         __fadd_rn(__fadd_rn(t[4], t[5]), __fadd_rn(t[6], t[7])));
    }
    float u[8];
#pragma unroll
    for (int i = 0; i < 8; ++i) u[i] = __fadd_rn(S[i], S[i + 8]);
    float v4[4];
#pragma unroll
    for (int i = 0; i < 4; ++i) v4[i] = __fadd_rn(u[i], u[i + 4]);
    return __fadd_rn(__fadd_rn(v4[0], v4[2]), __fadd_rn(v4[1], v4[3]));
}

__device__ __forceinline__ float np_sum256_sq(const float* __restrict__ p, int stride) {
    return __fadd_rn(np_half_sq(p, stride), np_half_sq(p + 128 * stride, stride));
}

__global__ __launch_bounds__(256) void e2_kernel(const float* __restrict__ emb,
                                                 float* __restrict__ e2) {
    int k = blockIdx.x * 256 + threadIdx.x;
    if (k < KCB) e2[k] = np_sum256_sq(emb + k * DIM, 1);
}

__global__ __launch_bounds__(256) void z2_kernel(const float* __restrict__ z,
                                                 float* __restrict__ z2,
                                                 unsigned long long* __restrict__ cand) {
    int n = blockIdx.x * 256 + threadIdx.x;
    z2[n] = np_sum256_sq(z + z_base(n), 1024);
    cand[n] = 0x7FFFFFFFFFFFFFFFULL;   // init for atomicMin (re-poisoned each call)
}

__device__ __forceinline__ unsigned long long pack_vi(float v, int i) {
    unsigned int u = __float_as_uint(v);
    unsigned int key = (u & 0x80000000u) ? ~u : u;   // monotone float->uint (finite)
    return ((unsigned long long)key << 32) | (unsigned int)i;
}

// smem: zs [0..8192) as [dd][256]; es [8192..8192+32*132) as [dd][132]
// (stride 132: 16B-aligned rows, staging writes 4-way max).
// After compute: redv [256][16] aliases [0..4096), redi aliases [4096..8192).
#define SMEM_FLOATS (8192 + 32 * 132)

#define FMA_ROW(i, zv)                                      \
    acc[i][0] = __builtin_fmaf(zv, eb0.x, acc[i][0]);       \
    acc[i][1] = __builtin_fmaf(zv, eb0.y, acc[i][1]);       \
    acc[i][2] = __builtin_fmaf(zv, eb0.z, acc[i][2]);       \
    acc[i][3] = __builtin_fmaf(zv, eb0.w, acc[i][3]);       \
    acc[i][4] = __builtin_fmaf(zv, eb1.x, acc[i][4]);       \
    acc[i][5] = __builtin_fmaf(zv, eb1.y, acc[i][5]);       \
    acc[i][6] = __builtin_fmaf(zv, eb1.z, acc[i][6]);       \
    acc[i][7] = __builtin_fmaf(zv, eb1.w, acc[i][7]);

__global__ __launch_bounds__(256) void dist_argmin_kernel(
    const float* __restrict__ z, const float* __restrict__ emb,
    const float* __restrict__ z2w, const float* __restrict__ e2w,
    unsigned long long* __restrict__ cand)
{
    __shared__ __align__(16) float smem[SMEM_FLOATS];
    float* zs = smem;            // [dd][256]
    float* es = smem + 8192;     // [dd][132]

    const int tid = threadIdx.x;
    const int tx = tid & 15;
    const int ty = tid >> 4;
    const int pt = blockIdx.x & 127;
    const int split = blockIdx.x >> 7;
    const int n0 = pt << 8;                 // 256 points per tile
    const int kbase = split << 8;           // 256 k per split

    const int zb = z_base(n0);

    float z2r[16];
#pragma unroll
    for (int i = 0; i < 16; ++i)
        z2r[i] = z2w[n0 + (i >> 2) * 64 + 4 * ty + (i & 3)];

    float bv[16];
    int   bi[16];
#pragma unroll
    for (int i = 0; i < 16; ++i) { bv[i] = __builtin_huge_valf(); bi[i] = 0; }

    // staging thread mapping
    const int sp4 = (tid & 63) << 2;        // point quad for z staging
    const int zd0 = tid >> 6;               // 0..3
    const int edd2 = (tid & 15) * 2;        // d pair for e staging
    const int ekb  = tid >> 4;              // 0..15

#pragma unroll 1
    for (int kt = 0; kt < 2; ++kt) {
        const int k0 = kbase + kt * BK;
        float acc[16][8];
#pragma unroll
        for (int i = 0; i < 16; ++i)
#pragma unroll
            for (int j = 0; j < 8; ++j) acc[i][j] = 0.0f;

#pragma unroll 1
        for (int dt = 0; dt < DIM / DT; ++dt) {
            const int dbase = dt * DT;
            __syncthreads();                // previous tile fully consumed
#pragma unroll
            for (int rr = 0; rr < 8; ++rr) {
                int dd = zd0 + 4 * rr;
                float4 v = *(const float4*)(z + zb + ((dbase + dd) << 10) + sp4);
                *(float4*)(zs + dd * 256 + sp4) = v;
            }
#pragma unroll
            for (int rr = 0; rr < 8; ++rr) {
                int kk = ekb + 16 * rr;
                float2 v = *(const float2*)(emb + (k0 + kk) * DIM + dbase + edd2);
                es[edd2 * 132 + kk] = v.x;
                es[(edd2 + 1) * 132 + kk] = v.y;
            }
            __syncthreads();
#pragma unroll 2
            for (int dd = 0; dd < DT; ++dd) {
                const float* zrow = zs + dd * 256;
                const float* erow = es + dd * 132;
                float4 eb0 = *(const float4*)(erow + 4 * tx);
                float4 eb1 = *(const float4*)(erow + 64 + 4 * tx);
                float4 za0 = *(const float4*)(zrow + 4 * ty);
                float4 za1 = *(const float4*)(zrow + 64 + 4 * ty);
                float4 za2 = *(const float4*)(zrow + 128 + 4 * ty);
                float4 za3 = *(const float4*)(zrow + 192 + 4 * ty);
                FMA_ROW(0, za0.x)
                FMA_ROW(1, za0.y)
                FMA_ROW(2, za0.z)
                FMA_ROW(3, za0.w)
                FMA_ROW(4, za1.x)
                FMA_ROW(5, za1.y)
                FMA_ROW(6, za1.z)
                FMA_ROW(7, za1.w)
                FMA_ROW(8, za2.x)
                FMA_ROW(9, za2.y)
                FMA_ROW(10, za2.z)
                FMA_ROW(11, za2.w)
                FMA_ROW(12, za3.x)
                FMA_ROW(13, za3.y)
                FMA_ROW(14, za3.z)
                FMA_ROW(15, za3.w)
            }
        }
        // distances exactly as ref: t1 = z2 + e2 ; d = t1 - 2*dot. k ascending.
#pragma unroll
        for (int j = 0; j < 8; ++j) {
            int k = k0 + (j >> 2) * 64 + 4 * tx + (j & 3);
            float e2v = e2w[k];
#pragma unroll
            for (int i = 0; i < 16; ++i) {
                float t1 = __fadd_rn(z2r[i], e2v);
                float dcur = __fsub_rn(t1, __fmul_rn(2.0f, acc[i][j]));
                if (dcur < bv[i]) { bv[i] = dcur; bi[i] = k; }   // strict <: first min
            }
        }
    }

    // block reduction over tx (16 threads per point row), np tie-break
    __syncthreads();
    float* redv = smem;                     // [256][16]
    int*   redi = (int*)(smem + 4096);      // [256][16]
#pragma unroll
    for (int i = 0; i < 16; ++i) {
        int row = (i >> 2) * 64 + 4 * ty + (i & 3);
        redv[row * 16 + tx] = bv[i];
        redi[row * 16 + tx] = bi[i];
    }
    __syncthreads();
    {
        float v = redv[tid * 16];
        int   i = redi[tid * 16];
#pragma unroll
        for (int t = 1; t < 16; ++t) {
            float v2 = redv[tid * 16 + t];
            int   i2 = redi[tid * 16 + t];
            if (v2 < v || (v2 == v && i2 < i)) { v = v2; i = i2; }
        }
        atomicMin(&cand[n0 + tid], pack_vi(v, i));
    }
}

__global__ __launch_bounds__(256) void zq_loss_kernel(
    const float* __restrict__ z, const float* __restrict__ emb,
    const unsigned long long* __restrict__ cand, float* __restrict__ zq,
    float* __restrict__ out_idx, double* __restrict__ parts)
{
    const int n = blockIdx.x * 256 + threadIdx.x;
    const int kk = (int)(unsigned int)(cand[n] & 0xFFFFFFFFULL);
    out_idx[n] = (float)kk;
    const float* er = emb + kk * DIM;
    const int zb = z_base(n);
    double s = 0.0;
#pragma unroll 8
    for (int d = 0; d < DIM; ++d) {
        float ev = er[d];
        float zv = z[zb + (d << 10)];
        zq[zb + (d << 10)] = ev;
        float df = ev - zv;
        s = fma((double)df, (double)df, s);
    }
    for (int off = 32; off; off >>= 1) s += __shfl_down(s, off, 64);
    __shared__ double sred[4];
    if ((threadIdx.x & 63) == 0) sred[threadIdx.x >> 6] = s;
    __syncthreads();
    if (threadIdx.x == 0)
        parts[blockIdx.x] = (sred[0] + sred[1]) + (sred[2] + sred[3]);
}

__global__ __launch_bounds__(128) void loss_final_kernel(
    const double* __restrict__ parts, float* __restrict__ out_loss)
{
    int t = threadIdx.x;
    double v = parts[t];
    for (int off = 32; off; off >>= 1) v += __shfl_down(v, off, 64);
    __shared__ double w2[2];
    if ((t & 63) == 0) w2[t >> 6] = v;
    __syncthreads();
    if (t == 0)
        out_loss[0] = (float)(1.25 * ((w2[0] + w2[1]) / 8388608.0));
}

extern "C" void kernel_launch(void* const* d_in, const int* in_sizes, int n_in,
                              void* d_out, int out_size, void* d_ws, size_t ws_size,
                              hipStream_t stream) {
    const float* z   = (const float*)d_in[0];
    const float* emb = (const float*)d_in[1];
    float* out = (float*)d_out;

    // ws: z2[32768] f32 | e2[1024] f32 | cand[32768] u64 | parts[128] f64
    float* z2w = (float*)d_ws;
    float* e2w = z2w + NPTS;
    unsigned long long* cand = (unsigned long long*)((char*)d_ws + 135168);
    double* parts = (double*)((char*)d_ws + 135168 + NPTS * 8);

    e2_kernel<<<KCB / 256, 256, 0, stream>>>(emb, e2w);
    z2_kernel<<<NPTS / 256, 256, 0, stream>>>(z, z2w, cand);
    dist_argmin_kernel<<<(NPTS / BPTS) * NSPLIT, 256, 0, stream>>>(z, emb, z2w, e2w, cand);
    zq_loss_kernel<<<NPTS / 256, 256, 0, stream>>>(z, emb, cand, out + ZQ_OFF,
                                                   out + IDX_OFF, parts);
    loss_final_kernel<<<1, 128, 0, stream>>>(parts, out + LOSS_OFF);
}